// Round 1
// baseline (1010.716 us; speedup 1.0000x reference)
//
#include <hip/hip_runtime.h>

#define FDIM 64

// ---------------- degree / norm precompute ----------------

__global__ void k_deg_init(float* __restrict__ deg, int n) {
    int i = blockIdx.x * 256 + threadIdx.x;
    if (i < n) deg[i] = 1.0f;  // self-loop
}

__global__ void k_deg_count(const int* __restrict__ dst, float* __restrict__ deg, int E) {
    int e = blockIdx.x * 256 + threadIdx.x;
    if (e < E) unsafeAtomicAdd(&deg[dst[e]], 1.0f);
}

__global__ void k_dinv(float* __restrict__ deg, int n) {
    int i = blockIdx.x * 256 + threadIdx.x;
    if (i < n) deg[i] = rsqrtf(deg[i]);  // deg >= 1 always (self-loop)
}

__global__ void k_edgew(const int* __restrict__ src, const int* __restrict__ dst,
                        const float* __restrict__ dinv, float* __restrict__ w, int E) {
    int e = blockIdx.x * 256 + threadIdx.x;
    if (e < E) w[e] = dinv[src[e]] * dinv[dst[e]];
}

// ---------------- dense transform: t = act(ain + bias) @ W; agg = t * dinv^2 ----
// One block = 64 threads = 64 rows. 8x8 micro-tile per thread.
// In-place safe when ain == agg: tile is fully staged to LDS before any write.

__global__ __launch_bounds__(64) void k_matmul(
    const float* ain, const float* __restrict__ Wm,
    const float* __restrict__ bias, int do_relu,
    const float* __restrict__ dinv,
    float* __restrict__ t, float* agg, int n)
{
    __shared__ float As[FDIM][FDIM + 1];   // +1 pad: conflict-free column reads
    __shared__ float Ws[FDIM * FDIM];
    int tid = threadIdx.x;
    int r0 = blockIdx.x * FDIM;

    const float4* W4 = (const float4*)Wm;
    float4* Ws4w = (float4*)Ws;
    #pragma unroll
    for (int i = 0; i < 16; ++i) Ws4w[tid + 64 * i] = W4[tid + 64 * i];

    #pragma unroll
    for (int i = 0; i < 16; ++i) {
        int idx = tid + 64 * i;
        int r = idx >> 4;        // 0..63
        int kq = idx & 15;       // float4 group along features
        float4 v = make_float4(0.f, 0.f, 0.f, 0.f);
        int R = r0 + r;
        if (R < n) {
            v = ((const float4*)ain)[(size_t)R * 16 + kq];
            if (bias != nullptr) {
                float4 b = ((const float4*)bias)[kq];
                v.x += b.x; v.y += b.y; v.z += b.z; v.w += b.w;
            }
            if (do_relu) {
                v.x = fmaxf(v.x, 0.f); v.y = fmaxf(v.y, 0.f);
                v.z = fmaxf(v.z, 0.f); v.w = fmaxf(v.w, 0.f);
            }
        }
        As[r][kq * 4 + 0] = v.x;
        As[r][kq * 4 + 1] = v.y;
        As[r][kq * 4 + 2] = v.z;
        As[r][kq * 4 + 3] = v.w;
    }
    __syncthreads();

    int rq = tid >> 3;   // 0..7 -> rows rq*8..+7
    int cq = tid & 7;    // 0..7 -> cols cq*8..+7
    float acc[8][8];
    #pragma unroll
    for (int i = 0; i < 8; ++i)
        #pragma unroll
        for (int j = 0; j < 8; ++j) acc[i][j] = 0.f;

    const float4* Ws4 = (const float4*)Ws;
    #pragma unroll 4
    for (int k = 0; k < FDIM; ++k) {
        float a[8];
        #pragma unroll
        for (int i = 0; i < 8; ++i) a[i] = As[rq * 8 + i][k];
        float4 w0 = Ws4[k * 16 + cq * 2];
        float4 w1 = Ws4[k * 16 + cq * 2 + 1];
        float wv[8] = {w0.x, w0.y, w0.z, w0.w, w1.x, w1.y, w1.z, w1.w};
        #pragma unroll
        for (int i = 0; i < 8; ++i)
            #pragma unroll
            for (int j = 0; j < 8; ++j)
                acc[i][j] = fmaf(a[i], wv[j], acc[i][j]);
    }

    #pragma unroll
    for (int i = 0; i < 8; ++i) {
        int R = r0 + rq * 8 + i;
        if (R >= n) break;
        float dv = dinv[R];
        float dv2 = dv * dv;
        float4 t0 = make_float4(acc[i][0], acc[i][1], acc[i][2], acc[i][3]);
        float4 t1 = make_float4(acc[i][4], acc[i][5], acc[i][6], acc[i][7]);
        ((float4*)t)[(size_t)R * 16 + cq * 2 + 0] = t0;
        ((float4*)t)[(size_t)R * 16 + cq * 2 + 1] = t1;
        float4 a0 = make_float4(t0.x * dv2, t0.y * dv2, t0.z * dv2, t0.w * dv2);
        float4 a1 = make_float4(t1.x * dv2, t1.y * dv2, t1.z * dv2, t1.w * dv2);
        ((float4*)agg)[(size_t)R * 16 + cq * 2 + 0] = a0;
        ((float4*)agg)[(size_t)R * 16 + cq * 2 + 1] = a1;
    }
}

// ---------------- edge scatter: agg[dst] += t[src] * w[e] ----------------
// One wave (64 lanes) per edge: coalesced 256B gather + coalesced 256B atomic row.

__global__ __launch_bounds__(256) void k_scatter(
    const int* __restrict__ src, const int* __restrict__ dst,
    const float* __restrict__ w, const float* __restrict__ t,
    float* __restrict__ agg, int E)
{
    long long idx = (long long)blockIdx.x * 256 + threadIdx.x;
    int e = (int)(idx >> 6);
    if (e >= E) return;
    int f = (int)(idx & 63);
    int s = src[e], d = dst[e];
    float val = t[(size_t)s * 64 + f] * w[e];
    unsafeAtomicAdd(&agg[(size_t)d * 64 + f], val);
}

// ---------------- pool (mean per graph) + final linear ----------------

__global__ __launch_bounds__(256) void k_pool(
    const float* __restrict__ agg, const float* __restrict__ b3,
    const int* __restrict__ batch, const float* __restrict__ Wlin,
    const float* __restrict__ blin, float* __restrict__ out,
    int n, int fout)
{
    int g = blockIdx.x;
    int tid = threadIdx.x;

    // batch is sorted: binary search [start, end) for graph g (all threads redundantly)
    int lo = 0, hi = n;
    while (lo < hi) { int mid = (lo + hi) >> 1; if (batch[mid] < g) lo = mid + 1; else hi = mid; }
    int start = lo;
    hi = n;
    while (lo < hi) { int mid = (lo + hi) >> 1; if (batch[mid] <= g) lo = mid + 1; else hi = mid; }
    int end = lo;

    int f = tid & 63, part = tid >> 6;  // 4 partial sums per feature
    float s = 0.f;
    for (int i = start + part; i < end; i += 4)
        s += agg[(size_t)i * 64 + f];

    __shared__ float red[4][64];
    __shared__ float pooled[64];
    red[part][f] = s;
    __syncthreads();
    if (tid < 64) {
        float v = red[0][tid] + red[1][tid] + red[2][tid] + red[3][tid];
        int cnt = end - start;
        pooled[tid] = (cnt > 0) ? (v / (float)cnt + b3[tid]) : 0.f;
    }
    __syncthreads();
    if (tid < fout) {
        float o = blin[tid];
        for (int k = 0; k < 64; ++k) o += pooled[k] * Wlin[k * fout + tid];
        out[(size_t)g * fout + tid] = o;
    }
}

// ---------------- launcher ----------------

extern "C" void kernel_launch(void* const* d_in, const int* in_sizes, int n_in,
                              void* d_out, int out_size, void* d_ws, size_t ws_size,
                              hipStream_t stream) {
    const float* x     = (const float*)d_in[0];
    const int*   ei    = (const int*)d_in[1];
    const int*   batch = (const int*)d_in[2];
    const float* W1 = (const float*)d_in[3];
    const float* b1 = (const float*)d_in[4];
    const float* W2 = (const float*)d_in[5];
    const float* b2 = (const float*)d_in[6];
    const float* W3 = (const float*)d_in[7];
    const float* b3 = (const float*)d_in[8];
    const float* Wl = (const float*)d_in[9];
    const float* bl = (const float*)d_in[10];

    int n = in_sizes[0] / 64;
    int E = in_sizes[1] / 2;
    int fout = in_sizes[10];
    int ngraphs = out_size / fout;

    const int* srcp = ei;       // edge_index[0] = message source
    const int* dstp = ei + E;   // edge_index[1] = aggregation target

    // workspace layout (floats): t[n*64] | agg[n*64] | deg[n] | w[E]  (~55.6 MB)
    float* ws  = (float*)d_ws;
    float* t   = ws;
    float* agg = t + (size_t)n * 64;
    float* deg = agg + (size_t)n * 64;   // becomes dinv after k_dinv
    float* w   = deg + n;

    int nb_n = (n + 255) / 256;
    int nb_e = (E + 255) / 256;
    int nb_mm = (n + 63) / 64;
    long long sc_threads = (long long)E * 64;
    int nb_sc = (int)((sc_threads + 255) / 256);

    k_deg_init<<<nb_n, 256, 0, stream>>>(deg, n);
    k_deg_count<<<nb_e, 256, 0, stream>>>(dstp, deg, E);
    k_dinv<<<nb_n, 256, 0, stream>>>(deg, n);
    k_edgew<<<nb_e, 256, 0, stream>>>(srcp, dstp, deg, w, E);

    // layer 1: h1 = relu(agg(x @ W1) + b1)   (bias+relu deferred into layer-2 load)
    k_matmul<<<nb_mm, 64, 0, stream>>>(x, W1, nullptr, 0, deg, t, agg, n);
    k_scatter<<<nb_sc, 256, 0, stream>>>(srcp, dstp, w, t, agg, E);
    // layer 2
    k_matmul<<<nb_mm, 64, 0, stream>>>(agg, W2, b1, 1, deg, t, agg, n);
    k_scatter<<<nb_sc, 256, 0, stream>>>(srcp, dstp, w, t, agg, E);
    // layer 3 (no relu after; b3 applied in pool)
    k_matmul<<<nb_mm, 64, 0, stream>>>(agg, W3, b2, 1, deg, t, agg, n);
    k_scatter<<<nb_sc, 256, 0, stream>>>(srcp, dstp, w, t, agg, E);

    k_pool<<<ngraphs, 256, 0, stream>>>(agg, b3, batch, Wl, bl, (float*)d_out, n, fout);
}

// Round 2
// 529.686 us; speedup vs baseline: 1.9081x; 1.9081x over previous
//
#include <hip/hip_runtime.h>

#define FDIM 64

// ================= CSR build =================

__global__ void k_zero_cnt(int* __restrict__ cnt, int n) {
    int i = blockIdx.x * 256 + threadIdx.x;
    if (i < n) cnt[i] = 0;
}

__global__ void k_count(const int* __restrict__ dst, int* __restrict__ cnt, int E) {
    int e = blockIdx.x * 256 + threadIdx.x;
    if (e < E) atomicAdd(&cnt[dst[e]], 1);
}

__global__ void k_dinv(const int* __restrict__ cnt, float* __restrict__ dinv, int n) {
    int i = blockIdx.x * 256 + threadIdx.x;
    if (i < n) dinv[i] = rsqrtf((float)cnt[i] + 1.0f);  // +1 self-loop
}

// --- 3-kernel exclusive scan over cnt[n] (1024 elems/block) ---

__global__ __launch_bounds__(256) void k_scan1(const int* __restrict__ cnt,
                                               int* __restrict__ excl,
                                               int* __restrict__ bsum, int n) {
    __shared__ int s[256];
    int tid = threadIdx.x;
    int base = blockIdx.x * 1024 + tid * 4;
    int v[4];
    #pragma unroll
    for (int j = 0; j < 4; ++j) v[j] = (base + j < n) ? cnt[base + j] : 0;
    int tsum = v[0] + v[1] + v[2] + v[3];
    s[tid] = tsum;
    __syncthreads();
    for (int off = 1; off < 256; off <<= 1) {
        int x = (tid >= off) ? s[tid - off] : 0;
        __syncthreads();
        s[tid] += x;
        __syncthreads();
    }
    if (tid == 255) bsum[blockIdx.x] = s[255];
    int run = s[tid] - tsum;  // exclusive
    #pragma unroll
    for (int j = 0; j < 4; ++j) {
        if (base + j < n) excl[base + j] = run;
        run += v[j];
    }
}

__global__ __launch_bounds__(128) void k_scan2(int* __restrict__ bsum, int nb) {
    __shared__ int s[128];
    int tid = threadIdx.x;
    int v = (tid < nb) ? bsum[tid] : 0;
    s[tid] = v;
    __syncthreads();
    for (int off = 1; off < 128; off <<= 1) {
        int x = (tid >= off) ? s[tid - off] : 0;
        __syncthreads();
        s[tid] += x;
        __syncthreads();
    }
    if (tid < nb) bsum[tid] = s[tid] - v;  // exclusive
}

__global__ __launch_bounds__(256) void k_scan3(const int* __restrict__ excl,
                                               const int* __restrict__ bsum,
                                               int* __restrict__ off,
                                               int* __restrict__ cursor, int n) {
    int i = blockIdx.x * 256 + threadIdx.x;
    if (i < n) {
        int o = excl[i] + bsum[i >> 10];
        off[i] = o;
        cursor[i] = o;
    }
}

__global__ void k_fill(const int* __restrict__ src, const int* __restrict__ dst,
                       const float* __restrict__ dinv, int* __restrict__ cursor,
                       int* __restrict__ csr_src, float* __restrict__ csr_w, int E) {
    int e = blockIdx.x * 256 + threadIdx.x;
    if (e < E) {
        int s = src[e], d = dst[e];
        int pos = atomicAdd(&cursor[d], 1);
        csr_src[pos] = s;
        csr_w[pos] = dinv[s] * dinv[d];
    }
}

// ================= dense transform: t = act(ain + bias) @ W =================
// One block = 64 threads = 64 rows, 8x8 micro-tile per thread.

__global__ __launch_bounds__(64) void k_matmul(
    const float* __restrict__ ain, const float* __restrict__ Wm,
    const float* __restrict__ bias, int do_relu,
    float* __restrict__ t, int n)
{
    __shared__ float As[FDIM][FDIM + 1];
    __shared__ float Ws[FDIM * FDIM];
    int tid = threadIdx.x;
    int r0 = blockIdx.x * FDIM;

    const float4* W4 = (const float4*)Wm;
    float4* Ws4w = (float4*)Ws;
    #pragma unroll
    for (int i = 0; i < 16; ++i) Ws4w[tid + 64 * i] = W4[tid + 64 * i];

    #pragma unroll
    for (int i = 0; i < 16; ++i) {
        int idx = tid + 64 * i;
        int r = idx >> 4;
        int kq = idx & 15;
        float4 v = make_float4(0.f, 0.f, 0.f, 0.f);
        int R = r0 + r;
        if (R < n) {
            v = ((const float4*)ain)[(size_t)R * 16 + kq];
            if (bias != nullptr) {
                float4 b = ((const float4*)bias)[kq];
                v.x += b.x; v.y += b.y; v.z += b.z; v.w += b.w;
            }
            if (do_relu) {
                v.x = fmaxf(v.x, 0.f); v.y = fmaxf(v.y, 0.f);
                v.z = fmaxf(v.z, 0.f); v.w = fmaxf(v.w, 0.f);
            }
        }
        As[r][kq * 4 + 0] = v.x;
        As[r][kq * 4 + 1] = v.y;
        As[r][kq * 4 + 2] = v.z;
        As[r][kq * 4 + 3] = v.w;
    }
    __syncthreads();

    int rq = tid >> 3;
    int cq = tid & 7;
    float acc[8][8];
    #pragma unroll
    for (int i = 0; i < 8; ++i)
        #pragma unroll
        for (int j = 0; j < 8; ++j) acc[i][j] = 0.f;

    const float4* Ws4 = (const float4*)Ws;
    #pragma unroll 4
    for (int k = 0; k < FDIM; ++k) {
        float a[8];
        #pragma unroll
        for (int i = 0; i < 8; ++i) a[i] = As[rq * 8 + i][k];
        float4 w0 = Ws4[k * 16 + cq * 2];
        float4 w1 = Ws4[k * 16 + cq * 2 + 1];
        float wv[8] = {w0.x, w0.y, w0.z, w0.w, w1.x, w1.y, w1.z, w1.w};
        #pragma unroll
        for (int i = 0; i < 8; ++i)
            #pragma unroll
            for (int j = 0; j < 8; ++j)
                acc[i][j] = fmaf(a[i], wv[j], acc[i][j]);
    }

    #pragma unroll
    for (int i = 0; i < 8; ++i) {
        int R = r0 + rq * 8 + i;
        if (R >= n) break;
        ((float4*)t)[(size_t)R * 16 + cq * 2 + 0] =
            make_float4(acc[i][0], acc[i][1], acc[i][2], acc[i][3]);
        ((float4*)t)[(size_t)R * 16 + cq * 2 + 1] =
            make_float4(acc[i][4], acc[i][5], acc[i][6], acc[i][7]);
    }
}

// ================= aggregate: agg[i] = t[i]*dinv[i]^2 + sum_j w_ij * t[j] ======
// One wave per dst node: lanes = 64 features. Neighbor ids/weights pre-loaded
// lane-parallel and broadcast via shuffle -> 1 row-gather per neighbor.

__global__ __launch_bounds__(256) void k_aggregate(
    const int* __restrict__ off, const int* __restrict__ end,
    const int* __restrict__ csr_src, const float* __restrict__ csr_w,
    const float* __restrict__ dinv, const float* __restrict__ t,
    float* __restrict__ agg, int n)
{
    long long idx = (long long)blockIdx.x * 256 + threadIdx.x;
    int i = (int)(idx >> 6);
    if (i >= n) return;
    int f = (int)(idx & 63);

    int s0 = off[i];
    int e1 = end[i];           // cursor after fill == row end
    float dv = dinv[i];
    float acc = t[(size_t)i * 64 + f] * dv * dv;

    for (int base = s0; base < e1; base += 64) {
        int m = e1 - base; if (m > 64) m = 64;
        int sv = 0; float wv = 0.f;
        if (f < m) { sv = csr_src[base + f]; wv = csr_w[base + f]; }
        for (int k = 0; k < m; ++k) {
            int s = __shfl(sv, k);
            float ww = __shfl(wv, k);
            acc = fmaf(t[(size_t)s * 64 + f], ww, acc);
        }
    }
    agg[(size_t)i * 64 + f] = acc;
}

// ================= pool =================

__global__ __launch_bounds__(256) void k_pool1(
    const float* __restrict__ agg, const int* __restrict__ batch,
    float* __restrict__ partial, int n)
{
    int g = blockIdx.x >> 3;
    int part = blockIdx.x & 7;
    int tid = threadIdx.x;

    int lo = 0, hi = n;
    while (lo < hi) { int mid = (lo + hi) >> 1; if (batch[mid] < g) lo = mid + 1; else hi = mid; }
    int start = lo;
    hi = n;
    while (lo < hi) { int mid = (lo + hi) >> 1; if (batch[mid] <= g) lo = mid + 1; else hi = mid; }
    int end = lo;

    int f = tid & 63, r = tid >> 6;       // 4 rows in flight per block
    float s = 0.f;
    for (int i = start + part * 4 + r; i < end; i += 32)
        s += agg[(size_t)i * 64 + f];

    __shared__ float red[4][64];
    red[r][f] = s;
    __syncthreads();
    if (tid < 64)
        partial[((size_t)g * 8 + part) * 64 + tid] =
            red[0][tid] + red[1][tid] + red[2][tid] + red[3][tid];
}

__global__ __launch_bounds__(64) void k_pool2(
    const float* __restrict__ partial, const int* __restrict__ batch,
    const float* __restrict__ b3, const float* __restrict__ Wlin,
    const float* __restrict__ blin, float* __restrict__ out,
    int n, int fout)
{
    int g = blockIdx.x;
    int tid = threadIdx.x;

    int lo = 0, hi = n;
    while (lo < hi) { int mid = (lo + hi) >> 1; if (batch[mid] < g) lo = mid + 1; else hi = mid; }
    int start = lo;
    hi = n;
    while (lo < hi) { int mid = (lo + hi) >> 1; if (batch[mid] <= g) lo = mid + 1; else hi = mid; }
    int cnt = lo - start;

    __shared__ float pooled[64];
    float v = 0.f;
    #pragma unroll
    for (int p = 0; p < 8; ++p) v += partial[((size_t)g * 8 + p) * 64 + tid];
    pooled[tid] = (cnt > 0) ? (v / (float)cnt + b3[tid]) : 0.f;
    __syncthreads();
    if (tid < fout) {
        float o = blin[tid];
        for (int k = 0; k < 64; ++k) o += pooled[k] * Wlin[k * fout + tid];
        out[(size_t)g * fout + tid] = o;
    }
}

// ================= launcher =================

extern "C" void kernel_launch(void* const* d_in, const int* in_sizes, int n_in,
                              void* d_out, int out_size, void* d_ws, size_t ws_size,
                              hipStream_t stream) {
    const float* x     = (const float*)d_in[0];
    const int*   ei    = (const int*)d_in[1];
    const int*   batch = (const int*)d_in[2];
    const float* W1 = (const float*)d_in[3];
    const float* b1 = (const float*)d_in[4];
    const float* W2 = (const float*)d_in[5];
    const float* b2 = (const float*)d_in[6];
    const float* W3 = (const float*)d_in[7];
    const float* b3 = (const float*)d_in[8];
    const float* Wl = (const float*)d_in[9];
    const float* bl = (const float*)d_in[10];

    int n = in_sizes[0] / 64;
    int E = in_sizes[1] / 2;
    int fout = in_sizes[10];
    int ngraphs = out_size / fout;

    const int* srcp = ei;
    const int* dstp = ei + E;

    // ws layout
    float* ws   = (float*)d_ws;
    float* t    = ws;                              // n*64
    float* agg  = t + (size_t)n * 64;              // n*64
    float* dinv = agg + (size_t)n * 64;            // n
    float* csr_w = dinv + n;                       // E
    float* partial = csr_w + E;                    // 64*8*64
    int* cnt    = (int*)(partial + 64 * 8 * 64);   // n
    int* offs   = cnt + n;                         // n
    int* cursor = offs + n;                        // n  (== row end after fill)
    int* excl   = cursor + n;                      // n
    int* csr_src = excl + n;                       // E
    int* bsum   = csr_src + E;                     // 128

    int nb_n = (n + 255) / 256;
    int nb_e = (E + 255) / 256;
    int nb_mm = (n + 63) / 64;
    int nb_scan = (n + 1023) / 1024;
    int nb_ag = (int)(((long long)n * 64 + 255) / 256);

    // CSR build (once, reused 3x)
    k_zero_cnt<<<nb_n, 256, 0, stream>>>(cnt, n);
    k_count<<<nb_e, 256, 0, stream>>>(dstp, cnt, E);
    k_dinv<<<nb_n, 256, 0, stream>>>(cnt, dinv, n);
    k_scan1<<<nb_scan, 256, 0, stream>>>(cnt, excl, bsum, n);
    k_scan2<<<1, 128, 0, stream>>>(bsum, nb_scan);
    k_scan3<<<nb_n, 256, 0, stream>>>(excl, bsum, offs, cursor, n);
    k_fill<<<nb_e, 256, 0, stream>>>(srcp, dstp, dinv, cursor, csr_src, csr_w, E);

    // layer 1
    k_matmul<<<nb_mm, 64, 0, stream>>>(x, W1, nullptr, 0, t, n);
    k_aggregate<<<nb_ag, 256, 0, stream>>>(offs, cursor, csr_src, csr_w, dinv, t, agg, n);
    // layer 2
    k_matmul<<<nb_mm, 64, 0, stream>>>(agg, W2, b1, 1, t, n);
    k_aggregate<<<nb_ag, 256, 0, stream>>>(offs, cursor, csr_src, csr_w, dinv, t, agg, n);
    // layer 3
    k_matmul<<<nb_mm, 64, 0, stream>>>(agg, W3, b2, 1, t, n);
    k_aggregate<<<nb_ag, 256, 0, stream>>>(offs, cursor, csr_src, csr_w, dinv, t, agg, n);

    // pool + linear
    k_pool1<<<ngraphs * 8, 256, 0, stream>>>(agg, batch, partial, n);
    k_pool2<<<ngraphs, 64, 0, stream>>>(partial, batch, b3, Wl, bl, (float*)d_out, n, fout);
}

// Round 3
// 412.361 us; speedup vs baseline: 2.4510x; 1.2845x over previous
//
#include <hip/hip_runtime.h>

#define FDIM 64

// ================= CSR build =================

__global__ void k_zero_cnt(int* __restrict__ cnt, int n) {
    int i = blockIdx.x * 256 + threadIdx.x;
    if (i < n) cnt[i] = 0;
}

__global__ void k_count(const int* __restrict__ dst, int* __restrict__ cnt, int E) {
    int e = blockIdx.x * 256 + threadIdx.x;
    if (e < E) atomicAdd(&cnt[dst[e]], 1);
}

__global__ void k_dinv(const int* __restrict__ cnt, float* __restrict__ dinv, int n) {
    int i = blockIdx.x * 256 + threadIdx.x;
    if (i < n) dinv[i] = rsqrtf((float)cnt[i] + 1.0f);  // +1 self-loop
}

// --- 3-kernel exclusive scan over cnt[n] (1024 elems/block) ---

__global__ __launch_bounds__(256) void k_scan1(const int* __restrict__ cnt,
                                               int* __restrict__ excl,
                                               int* __restrict__ bsum, int n) {
    __shared__ int s[256];
    int tid = threadIdx.x;
    int base = blockIdx.x * 1024 + tid * 4;
    int v[4];
    #pragma unroll
    for (int j = 0; j < 4; ++j) v[j] = (base + j < n) ? cnt[base + j] : 0;
    int tsum = v[0] + v[1] + v[2] + v[3];
    s[tid] = tsum;
    __syncthreads();
    for (int off = 1; off < 256; off <<= 1) {
        int x = (tid >= off) ? s[tid - off] : 0;
        __syncthreads();
        s[tid] += x;
        __syncthreads();
    }
    if (tid == 255) bsum[blockIdx.x] = s[255];
    int run = s[tid] - tsum;  // exclusive
    #pragma unroll
    for (int j = 0; j < 4; ++j) {
        if (base + j < n) excl[base + j] = run;
        run += v[j];
    }
}

__global__ __launch_bounds__(128) void k_scan2(int* __restrict__ bsum, int nb) {
    __shared__ int s[128];
    int tid = threadIdx.x;
    int v = (tid < nb) ? bsum[tid] : 0;
    s[tid] = v;
    __syncthreads();
    for (int off = 1; off < 128; off <<= 1) {
        int x = (tid >= off) ? s[tid - off] : 0;
        __syncthreads();
        s[tid] += x;
        __syncthreads();
    }
    if (tid < nb) bsum[tid] = s[tid] - v;  // exclusive
}

__global__ __launch_bounds__(256) void k_scan3(const int* __restrict__ excl,
                                               const int* __restrict__ bsum,
                                               int* __restrict__ off,
                                               int* __restrict__ cursor, int n) {
    int i = blockIdx.x * 256 + threadIdx.x;
    if (i < n) {
        int o = excl[i] + bsum[i >> 10];
        off[i] = o;
        cursor[i] = o;
    }
}

__global__ void k_fill(const int* __restrict__ src, const int* __restrict__ dst,
                       const float* __restrict__ dinv, int* __restrict__ cursor,
                       int* __restrict__ csr_src, float* __restrict__ csr_w, int E) {
    int e = blockIdx.x * 256 + threadIdx.x;
    if (e < E) {
        int s = src[e], d = dst[e];
        int pos = atomicAdd(&cursor[d], 1);
        csr_src[pos] = s;
        csr_w[pos] = dinv[s] * dinv[d];
    }
}

// ================= dense transform: t = act(ain + bias) @ W =================
// 256 threads / 128 rows per block; thread = 8 rows x 4 cols micro-tile.
// As[r][65]: a-reads are 4-address 16-lane broadcasts (conflict-free);
// staged writes land 2 lanes/bank (free). W float4 reads are wave-broadcast.

__global__ __launch_bounds__(256) void k_matmul(
    const float* __restrict__ ain, const float* __restrict__ Wm,
    const float* __restrict__ bias, int do_relu,
    float* __restrict__ t, int n)
{
    __shared__ float As[128][FDIM + 1];
    __shared__ float Ws[FDIM * FDIM];
    int tid = threadIdx.x;
    int r0 = blockIdx.x * 128;

    const float4* W4 = (const float4*)Wm;
    float4* Ws4w = (float4*)Ws;
    #pragma unroll
    for (int i = 0; i < 4; ++i) Ws4w[tid + 256 * i] = W4[tid + 256 * i];

    #pragma unroll
    for (int i = 0; i < 8; ++i) {
        int idx = tid + 256 * i;
        int r = idx >> 4;        // 0..127
        int kq = idx & 15;       // float4 group
        float4 v = make_float4(0.f, 0.f, 0.f, 0.f);
        int R = r0 + r;
        if (R < n) {
            v = ((const float4*)ain)[(size_t)R * 16 + kq];
            if (bias != nullptr) {
                float4 b = ((const float4*)bias)[kq];
                v.x += b.x; v.y += b.y; v.z += b.z; v.w += b.w;
            }
            if (do_relu) {
                v.x = fmaxf(v.x, 0.f); v.y = fmaxf(v.y, 0.f);
                v.z = fmaxf(v.z, 0.f); v.w = fmaxf(v.w, 0.f);
            }
        }
        As[r][kq * 4 + 0] = v.x;
        As[r][kq * 4 + 1] = v.y;
        As[r][kq * 4 + 2] = v.z;
        As[r][kq * 4 + 3] = v.w;
    }
    __syncthreads();

    int rq = tid >> 4;   // 0..15 -> rows rq*8..+7
    int cq = tid & 15;   // 0..15 -> cols cq*4..+3
    float acc[8][4];
    #pragma unroll
    for (int i = 0; i < 8; ++i)
        #pragma unroll
        for (int j = 0; j < 4; ++j) acc[i][j] = 0.f;

    const float4* Ws4 = (const float4*)Ws;
    #pragma unroll 4
    for (int k = 0; k < FDIM; ++k) {
        float4 w = Ws4[k * 16 + cq];
        float a[8];
        #pragma unroll
        for (int i = 0; i < 8; ++i) a[i] = As[rq * 8 + i][k];
        #pragma unroll
        for (int i = 0; i < 8; ++i) {
            acc[i][0] = fmaf(a[i], w.x, acc[i][0]);
            acc[i][1] = fmaf(a[i], w.y, acc[i][1]);
            acc[i][2] = fmaf(a[i], w.z, acc[i][2]);
            acc[i][3] = fmaf(a[i], w.w, acc[i][3]);
        }
    }

    #pragma unroll
    for (int i = 0; i < 8; ++i) {
        int R = r0 + rq * 8 + i;
        if (R < n)
            ((float4*)t)[(size_t)R * 16 + cq] =
                make_float4(acc[i][0], acc[i][1], acc[i][2], acc[i][3]);
    }
}

// ================= aggregate: agg[i] = t[i]*dinv[i]^2 + sum_j w_ij * t[j] ======
// One wave per dst node, lanes = features. 4-way unroll: 4 independent row
// gathers in flight per iteration to hide L2/L3 latency.

__global__ __launch_bounds__(256) void k_aggregate(
    const int* __restrict__ off, const int* __restrict__ end,
    const int* __restrict__ csr_src, const float* __restrict__ csr_w,
    const float* __restrict__ dinv, const float* __restrict__ t,
    float* __restrict__ agg, int n)
{
    long long idx = (long long)blockIdx.x * 256 + threadIdx.x;
    int i = (int)(idx >> 6);
    if (i >= n) return;
    int f = (int)(idx & 63);

    int s0 = off[i];
    int e1 = end[i];
    float dv = dinv[i];
    float a0 = t[(size_t)i * 64 + f] * dv * dv;
    float a1 = 0.f, a2 = 0.f, a3 = 0.f;

    for (int base = s0; base < e1; base += 64) {
        int m = e1 - base; if (m > 64) m = 64;
        int sv = 0; float wv = 0.f;
        if (f < m) { sv = csr_src[base + f]; wv = csr_w[base + f]; }
        int k = 0;
        for (; k + 4 <= m; k += 4) {
            int j0 = __shfl(sv, k + 0);
            int j1 = __shfl(sv, k + 1);
            int j2 = __shfl(sv, k + 2);
            int j3 = __shfl(sv, k + 3);
            float w0 = __shfl(wv, k + 0);
            float w1 = __shfl(wv, k + 1);
            float w2 = __shfl(wv, k + 2);
            float w3 = __shfl(wv, k + 3);
            float v0 = t[(size_t)j0 * 64 + f];
            float v1 = t[(size_t)j1 * 64 + f];
            float v2 = t[(size_t)j2 * 64 + f];
            float v3 = t[(size_t)j3 * 64 + f];
            a0 = fmaf(v0, w0, a0);
            a1 = fmaf(v1, w1, a1);
            a2 = fmaf(v2, w2, a2);
            a3 = fmaf(v3, w3, a3);
        }
        for (; k < m; ++k) {
            int j = __shfl(sv, k);
            float ww = __shfl(wv, k);
            a0 = fmaf(t[(size_t)j * 64 + f], ww, a0);
        }
    }
    agg[(size_t)i * 64 + f] = (a0 + a1) + (a2 + a3);
}

// ================= pool =================

__global__ __launch_bounds__(256) void k_pool1(
    const float* __restrict__ agg, const int* __restrict__ batch,
    float* __restrict__ partial, int n)
{
    int g = blockIdx.x >> 3;
    int part = blockIdx.x & 7;
    int tid = threadIdx.x;

    int lo = 0, hi = n;
    while (lo < hi) { int mid = (lo + hi) >> 1; if (batch[mid] < g) lo = mid + 1; else hi = mid; }
    int start = lo;
    hi = n;
    while (lo < hi) { int mid = (lo + hi) >> 1; if (batch[mid] <= g) lo = mid + 1; else hi = mid; }
    int end = lo;

    int f = tid & 63, r = tid >> 6;
    float s = 0.f;
    for (int i = start + part * 4 + r; i < end; i += 32)
        s += agg[(size_t)i * 64 + f];

    __shared__ float red[4][64];
    red[r][f] = s;
    __syncthreads();
    if (tid < 64)
        partial[((size_t)g * 8 + part) * 64 + tid] =
            red[0][tid] + red[1][tid] + red[2][tid] + red[3][tid];
}

__global__ __launch_bounds__(64) void k_pool2(
    const float* __restrict__ partial, const int* __restrict__ batch,
    const float* __restrict__ b3, const float* __restrict__ Wlin,
    const float* __restrict__ blin, float* __restrict__ out,
    int n, int fout)
{
    int g = blockIdx.x;
    int tid = threadIdx.x;

    int lo = 0, hi = n;
    while (lo < hi) { int mid = (lo + hi) >> 1; if (batch[mid] < g) lo = mid + 1; else hi = mid; }
    int start = lo;
    hi = n;
    while (lo < hi) { int mid = (lo + hi) >> 1; if (batch[mid] <= g) lo = mid + 1; else hi = mid; }
    int cnt = lo - start;

    __shared__ float pooled[64];
    float v = 0.f;
    #pragma unroll
    for (int p = 0; p < 8; ++p) v += partial[((size_t)g * 8 + p) * 64 + tid];
    pooled[tid] = (cnt > 0) ? (v / (float)cnt + b3[tid]) : 0.f;
    __syncthreads();
    if (tid < fout) {
        float o = blin[tid];
        for (int k = 0; k < 64; ++k) o += pooled[k] * Wlin[k * fout + tid];
        out[(size_t)g * fout + tid] = o;
    }
}

// ================= launcher =================

extern "C" void kernel_launch(void* const* d_in, const int* in_sizes, int n_in,
                              void* d_out, int out_size, void* d_ws, size_t ws_size,
                              hipStream_t stream) {
    const float* x     = (const float*)d_in[0];
    const int*   ei    = (const int*)d_in[1];
    const int*   batch = (const int*)d_in[2];
    const float* W1 = (const float*)d_in[3];
    const float* b1 = (const float*)d_in[4];
    const float* W2 = (const float*)d_in[5];
    const float* b2 = (const float*)d_in[6];
    const float* W3 = (const float*)d_in[7];
    const float* b3 = (const float*)d_in[8];
    const float* Wl = (const float*)d_in[9];
    const float* bl = (const float*)d_in[10];

    int n = in_sizes[0] / 64;
    int E = in_sizes[1] / 2;
    int fout = in_sizes[10];
    int ngraphs = out_size / fout;

    const int* srcp = ei;
    const int* dstp = ei + E;

    // ws layout
    float* ws   = (float*)d_ws;
    float* t    = ws;                              // n*64
    float* agg  = t + (size_t)n * 64;              // n*64
    float* dinv = agg + (size_t)n * 64;            // n
    float* csr_w = dinv + n;                       // E
    float* partial = csr_w + E;                    // 64*8*64
    int* cnt    = (int*)(partial + 64 * 8 * 64);   // n
    int* offs   = cnt + n;                         // n
    int* cursor = offs + n;                        // n  (== row end after fill)
    int* excl   = cursor + n;                      // n
    int* csr_src = excl + n;                       // E
    int* bsum   = csr_src + E;                     // 128

    int nb_n = (n + 255) / 256;
    int nb_e = (E + 255) / 256;
    int nb_mm = (n + 127) / 128;
    int nb_scan = (n + 1023) / 1024;
    int nb_ag = (int)(((long long)n * 64 + 255) / 256);

    // CSR build (once, reused 3x)
    k_zero_cnt<<<nb_n, 256, 0, stream>>>(cnt, n);
    k_count<<<nb_e, 256, 0, stream>>>(dstp, cnt, E);
    k_dinv<<<nb_n, 256, 0, stream>>>(cnt, dinv, n);
    k_scan1<<<nb_scan, 256, 0, stream>>>(cnt, excl, bsum, n);
    k_scan2<<<1, 128, 0, stream>>>(bsum, nb_scan);
    k_scan3<<<nb_n, 256, 0, stream>>>(excl, bsum, offs, cursor, n);
    k_fill<<<nb_e, 256, 0, stream>>>(srcp, dstp, dinv, cursor, csr_src, csr_w, E);

    // layer 1
    k_matmul<<<nb_mm, 256, 0, stream>>>(x, W1, nullptr, 0, t, n);
    k_aggregate<<<nb_ag, 256, 0, stream>>>(offs, cursor, csr_src, csr_w, dinv, t, agg, n);
    // layer 2
    k_matmul<<<nb_mm, 256, 0, stream>>>(agg, W2, b1, 1, t, n);
    k_aggregate<<<nb_ag, 256, 0, stream>>>(offs, cursor, csr_src, csr_w, dinv, t, agg, n);
    // layer 3
    k_matmul<<<nb_mm, 256, 0, stream>>>(agg, W3, b2, 1, t, n);
    k_aggregate<<<nb_ag, 256, 0, stream>>>(offs, cursor, csr_src, csr_w, dinv, t, agg, n);

    // pool + linear
    k_pool1<<<ngraphs * 8, 256, 0, stream>>>(agg, batch, partial, n);
    k_pool2<<<ngraphs, 64, 0, stream>>>(partial, batch, b3, Wl, bl, (float*)d_out, n, fout);
}

// Round 4
// 400.727 us; speedup vs baseline: 2.5222x; 1.0290x over previous
//
#include <hip/hip_runtime.h>

#define FDIM 64

// ================= CSR build =================

__global__ void k_count(const int* __restrict__ dst, int* __restrict__ cnt, int E) {
    int e = blockIdx.x * 256 + threadIdx.x;
    if (e < E) atomicAdd(&cnt[dst[e]], 1);
}

// --- 3-kernel exclusive scan over cnt[n] (1024 elems/block); also emits dinv ---

__global__ __launch_bounds__(256) void k_scan1(const int* __restrict__ cnt,
                                               int* __restrict__ excl,
                                               int* __restrict__ bsum,
                                               float* __restrict__ dinv, int n) {
    __shared__ int s[256];
    int tid = threadIdx.x;
    int base = blockIdx.x * 1024 + tid * 4;
    int v[4];
    #pragma unroll
    for (int j = 0; j < 4; ++j) v[j] = (base + j < n) ? cnt[base + j] : 0;
    #pragma unroll
    for (int j = 0; j < 4; ++j)
        if (base + j < n) dinv[base + j] = rsqrtf((float)v[j] + 1.0f);  // +1 self-loop
    int tsum = v[0] + v[1] + v[2] + v[3];
    s[tid] = tsum;
    __syncthreads();
    for (int off = 1; off < 256; off <<= 1) {
        int x = (tid >= off) ? s[tid - off] : 0;
        __syncthreads();
        s[tid] += x;
        __syncthreads();
    }
    if (tid == 255) bsum[blockIdx.x] = s[255];
    int run = s[tid] - tsum;  // exclusive
    #pragma unroll
    for (int j = 0; j < 4; ++j) {
        if (base + j < n) excl[base + j] = run;
        run += v[j];
    }
}

__global__ __launch_bounds__(128) void k_scan2(int* __restrict__ bsum, int nb) {
    __shared__ int s[128];
    int tid = threadIdx.x;
    int v = (tid < nb) ? bsum[tid] : 0;
    s[tid] = v;
    __syncthreads();
    for (int off = 1; off < 128; off <<= 1) {
        int x = (tid >= off) ? s[tid - off] : 0;
        __syncthreads();
        s[tid] += x;
        __syncthreads();
    }
    if (tid < nb) bsum[tid] = s[tid] - v;  // exclusive
}

__global__ __launch_bounds__(256) void k_scan3(const int* __restrict__ excl,
                                               const int* __restrict__ bsum,
                                               int* __restrict__ off,
                                               int* __restrict__ cursor, int n) {
    int i = blockIdx.x * 256 + threadIdx.x;
    if (i < n) {
        int o = excl[i] + bsum[i >> 10];
        off[i] = o;
        cursor[i] = o;
    }
}

// one 8B scattered write per edge: (src, weight-bits)
__global__ void k_fill(const int* __restrict__ src, const int* __restrict__ dst,
                       const float* __restrict__ dinv, int* __restrict__ cursor,
                       int2* __restrict__ csr, int E) {
    int e = blockIdx.x * 256 + threadIdx.x;
    if (e < E) {
        int s = src[e], d = dst[e];
        int pos = atomicAdd(&cursor[d], 1);
        int2 p;
        p.x = s;
        p.y = __float_as_int(dinv[s] * dinv[d]);
        csr[pos] = p;
    }
}

// ================= dense transform: t = act(ain + bias) @ W =================
// 256 threads / 128 rows per block; thread = 8 rows x 4 cols micro-tile.

__global__ __launch_bounds__(256) void k_matmul(
    const float* __restrict__ ain, const float* __restrict__ Wm,
    const float* __restrict__ bias, int do_relu,
    float* __restrict__ t, int n)
{
    __shared__ float As[128][FDIM + 1];
    __shared__ float Ws[FDIM * FDIM];
    int tid = threadIdx.x;
    int r0 = blockIdx.x * 128;

    const float4* W4 = (const float4*)Wm;
    float4* Ws4w = (float4*)Ws;
    #pragma unroll
    for (int i = 0; i < 4; ++i) Ws4w[tid + 256 * i] = W4[tid + 256 * i];

    #pragma unroll
    for (int i = 0; i < 8; ++i) {
        int idx = tid + 256 * i;
        int r = idx >> 4;
        int kq = idx & 15;
        float4 v = make_float4(0.f, 0.f, 0.f, 0.f);
        int R = r0 + r;
        if (R < n) {
            v = ((const float4*)ain)[(size_t)R * 16 + kq];
            if (bias != nullptr) {
                float4 b = ((const float4*)bias)[kq];
                v.x += b.x; v.y += b.y; v.z += b.z; v.w += b.w;
            }
            if (do_relu) {
                v.x = fmaxf(v.x, 0.f); v.y = fmaxf(v.y, 0.f);
                v.z = fmaxf(v.z, 0.f); v.w = fmaxf(v.w, 0.f);
            }
        }
        As[r][kq * 4 + 0] = v.x;
        As[r][kq * 4 + 1] = v.y;
        As[r][kq * 4 + 2] = v.z;
        As[r][kq * 4 + 3] = v.w;
    }
    __syncthreads();

    int rq = tid >> 4;
    int cq = tid & 15;
    float acc[8][4];
    #pragma unroll
    for (int i = 0; i < 8; ++i)
        #pragma unroll
        for (int j = 0; j < 4; ++j) acc[i][j] = 0.f;

    const float4* Ws4 = (const float4*)Ws;
    #pragma unroll 4
    for (int k = 0; k < FDIM; ++k) {
        float4 w = Ws4[k * 16 + cq];
        float a[8];
        #pragma unroll
        for (int i = 0; i < 8; ++i) a[i] = As[rq * 8 + i][k];
        #pragma unroll
        for (int i = 0; i < 8; ++i) {
            acc[i][0] = fmaf(a[i], w.x, acc[i][0]);
            acc[i][1] = fmaf(a[i], w.y, acc[i][1]);
            acc[i][2] = fmaf(a[i], w.z, acc[i][2]);
            acc[i][3] = fmaf(a[i], w.w, acc[i][3]);
        }
    }

    #pragma unroll
    for (int i = 0; i < 8; ++i) {
        int R = r0 + rq * 8 + i;
        if (R < n)
            ((float4*)t)[(size_t)R * 16 + cq] =
                make_float4(acc[i][0], acc[i][1], acc[i][2], acc[i][3]);
    }
}

// ================= aggregate: agg[i] = t[i]*dinv[i]^2 + sum_j w_ij * t[j] ======
// One wave per dst node, lanes = features. 8-wide gather batches for MLP.

__global__ __launch_bounds__(256) void k_aggregate(
    const int* __restrict__ off, const int* __restrict__ end,
    const int2* __restrict__ csr, const float* __restrict__ dinv,
    const float* __restrict__ t, float* __restrict__ agg, int n)
{
    long long idx = (long long)blockIdx.x * 256 + threadIdx.x;
    int i = (int)(idx >> 6);
    if (i >= n) return;
    int f = (int)(idx & 63);

    int s0 = off[i];
    int e1 = end[i];
    float dv = dinv[i];
    float a0 = t[(size_t)i * 64 + f] * dv * dv;
    float a1 = 0.f, a2 = 0.f, a3 = 0.f;

    for (int base = s0; base < e1; base += 64) {
        int m = e1 - base; if (m > 64) m = 64;
        int2 cw = make_int2(0, 0);
        if (f < m) cw = csr[base + f];
        int k = 0;
        for (; k + 8 <= m; k += 8) {
            int jv[8]; float wv[8], v[8];
            #pragma unroll
            for (int u = 0; u < 8; ++u) {
                jv[u] = __shfl(cw.x, k + u);
                wv[u] = __int_as_float(__shfl(cw.y, k + u));
            }
            #pragma unroll
            for (int u = 0; u < 8; ++u) v[u] = t[(size_t)jv[u] * 64 + f];
            a0 = fmaf(v[0], wv[0], a0);
            a1 = fmaf(v[1], wv[1], a1);
            a2 = fmaf(v[2], wv[2], a2);
            a3 = fmaf(v[3], wv[3], a3);
            a0 = fmaf(v[4], wv[4], a0);
            a1 = fmaf(v[5], wv[5], a1);
            a2 = fmaf(v[6], wv[6], a2);
            a3 = fmaf(v[7], wv[7], a3);
        }
        if (k + 4 <= m) {
            int jv[4]; float wv[4], v[4];
            #pragma unroll
            for (int u = 0; u < 4; ++u) {
                jv[u] = __shfl(cw.x, k + u);
                wv[u] = __int_as_float(__shfl(cw.y, k + u));
            }
            #pragma unroll
            for (int u = 0; u < 4; ++u) v[u] = t[(size_t)jv[u] * 64 + f];
            a0 = fmaf(v[0], wv[0], a0);
            a1 = fmaf(v[1], wv[1], a1);
            a2 = fmaf(v[2], wv[2], a2);
            a3 = fmaf(v[3], wv[3], a3);
            k += 4;
        }
        for (; k < m; ++k) {
            int j = __shfl(cw.x, k);
            float ww = __int_as_float(__shfl(cw.y, k));
            a0 = fmaf(t[(size_t)j * 64 + f], ww, a0);
        }
    }
    agg[(size_t)i * 64 + f] = (a0 + a1) + (a2 + a3);
}

// ================= pool =================

__global__ __launch_bounds__(256) void k_pool1(
    const float* __restrict__ agg, const int* __restrict__ batch,
    float* __restrict__ partial, int n)
{
    int g = blockIdx.x >> 3;
    int part = blockIdx.x & 7;
    int tid = threadIdx.x;

    int lo = 0, hi = n;
    while (lo < hi) { int mid = (lo + hi) >> 1; if (batch[mid] < g) lo = mid + 1; else hi = mid; }
    int start = lo;
    hi = n;
    while (lo < hi) { int mid = (lo + hi) >> 1; if (batch[mid] <= g) lo = mid + 1; else hi = mid; }
    int end = lo;

    int f = tid & 63, r = tid >> 6;
    float s = 0.f;
    for (int i = start + part * 4 + r; i < end; i += 32)
        s += agg[(size_t)i * 64 + f];

    __shared__ float red[4][64];
    red[r][f] = s;
    __syncthreads();
    if (tid < 64)
        partial[((size_t)g * 8 + part) * 64 + tid] =
            red[0][tid] + red[1][tid] + red[2][tid] + red[3][tid];
}

__global__ __launch_bounds__(64) void k_pool2(
    const float* __restrict__ partial, const int* __restrict__ batch,
    const float* __restrict__ b3, const float* __restrict__ Wlin,
    const float* __restrict__ blin, float* __restrict__ out,
    int n, int fout)
{
    int g = blockIdx.x;
    int tid = threadIdx.x;

    int lo = 0, hi = n;
    while (lo < hi) { int mid = (lo + hi) >> 1; if (batch[mid] < g) lo = mid + 1; else hi = mid; }
    int start = lo;
    hi = n;
    while (lo < hi) { int mid = (lo + hi) >> 1; if (batch[mid] <= g) lo = mid + 1; else hi = mid; }
    int cnt = lo - start;

    __shared__ float pooled[64];
    float v = 0.f;
    #pragma unroll
    for (int p = 0; p < 8; ++p) v += partial[((size_t)g * 8 + p) * 64 + tid];
    pooled[tid] = (cnt > 0) ? (v / (float)cnt + b3[tid]) : 0.f;
    __syncthreads();
    if (tid < fout) {
        float o = blin[tid];
        for (int k = 0; k < 64; ++k) o += pooled[k] * Wlin[k * fout + tid];
        out[(size_t)g * fout + tid] = o;
    }
}

// ================= launcher =================

extern "C" void kernel_launch(void* const* d_in, const int* in_sizes, int n_in,
                              void* d_out, int out_size, void* d_ws, size_t ws_size,
                              hipStream_t stream) {
    const float* x     = (const float*)d_in[0];
    const int*   ei    = (const int*)d_in[1];
    const int*   batch = (const int*)d_in[2];
    const float* W1 = (const float*)d_in[3];
    const float* b1 = (const float*)d_in[4];
    const float* W2 = (const float*)d_in[5];
    const float* b2 = (const float*)d_in[6];
    const float* W3 = (const float*)d_in[7];
    const float* b3 = (const float*)d_in[8];
    const float* Wl = (const float*)d_in[9];
    const float* bl = (const float*)d_in[10];

    int n = in_sizes[0] / 64;
    int E = in_sizes[1] / 2;
    int fout = in_sizes[10];
    int ngraphs = out_size / fout;

    const int* srcp = ei;
    const int* dstp = ei + E;

    // ws layout (floats) — csr (int2) placed at even-float offset for 8B alignment
    float* ws   = (float*)d_ws;
    float* t    = ws;                              // n*64
    float* agg  = t + (size_t)n * 64;              // n*64
    int2*  csr  = (int2*)(agg + (size_t)n * 64);   // E int2
    float* dinv = (float*)(csr + E);               // n
    float* partial = dinv + n;                     // 64*8*64
    int* cnt    = (int*)(partial + 64 * 8 * 64);   // n
    int* offs   = cnt + n;                         // n
    int* cursor = offs + n;                        // n  (== row end after fill)
    int* excl   = cursor + n;                      // n
    int* bsum   = excl + n;                        // 128

    int nb_n = (n + 255) / 256;
    int nb_e = (E + 255) / 256;
    int nb_mm = (n + 127) / 128;
    int nb_scan = (n + 1023) / 1024;
    int nb_ag = (int)(((long long)n * 64 + 255) / 256);

    // CSR build (once, reused 3x)
    hipMemsetAsync(cnt, 0, (size_t)n * sizeof(int), stream);
    k_count<<<nb_e, 256, 0, stream>>>(dstp, cnt, E);
    k_scan1<<<nb_scan, 256, 0, stream>>>(cnt, excl, bsum, dinv, n);
    k_scan2<<<1, 128, 0, stream>>>(bsum, nb_scan);
    k_scan3<<<nb_n, 256, 0, stream>>>(excl, bsum, offs, cursor, n);
    k_fill<<<nb_e, 256, 0, stream>>>(srcp, dstp, dinv, cursor, csr, E);

    // layer 1
    k_matmul<<<nb_mm, 256, 0, stream>>>(x, W1, nullptr, 0, t, n);
    k_aggregate<<<nb_ag, 256, 0, stream>>>(offs, cursor, csr, dinv, t, agg, n);
    // layer 2
    k_matmul<<<nb_mm, 256, 0, stream>>>(agg, W2, b1, 1, t, n);
    k_aggregate<<<nb_ag, 256, 0, stream>>>(offs, cursor, csr, dinv, t, agg, n);
    // layer 3
    k_matmul<<<nb_mm, 256, 0, stream>>>(agg, W3, b2, 1, t, n);
    k_aggregate<<<nb_ag, 256, 0, stream>>>(offs, cursor, csr, dinv, t, agg, n);

    // pool + linear
    k_pool1<<<ngraphs * 8, 256, 0, stream>>>(agg, batch, partial, n);
    k_pool2<<<ngraphs, 64, 0, stream>>>(partial, batch, b3, Wl, bl, (float*)d_out, n, fout);
}